// Round 9
// baseline (233.983 us; speedup 1.0000x reference)
//
#include <hip/hip_runtime.h>
#include <cstdint>
#include <cstddef>

// ---------------------------------------------------------------------------
// DHSEncoderLayer on MI355X (gfx950).  Round 12 = Round 11 (207.6 us) with
// K-destaged attention:
//  - K fragment reads are wave-contiguous 1KB blocks shared by all 4 waves
//    (L1-broadcast, L2-backstopped) -> read K directly from global everywhere;
//    Ks LDS buffers, their ds-traffic and prefetch chains removed. V stays
//    staged (transpose gather, genuinely load-bearing) with its one
//    barrier/chunk.  aw-pass prepass is now barrier-free and LDS-free.
//  - Everything else byte-identical to R11.
// B=4,S=2048,D=128,H=4,HD=32,V=64, ITERS=3. Outputs: x [B,S,D] f32, aw [B,H,S,S] f32.
// 9 dispatches: prep, qkv, [attn, wqkv]x3(last wqkv does ln2+colsum), uber.
// ---------------------------------------------------------------------------

typedef unsigned short u16;
typedef __attribute__((ext_vector_type(8))) short short8;   // 8 x bf16
typedef __attribute__((ext_vector_type(4))) float f32x4;
typedef __attribute__((ext_vector_type(2))) unsigned uint32x2;

#define B_ 4
#define S_ 2048
#define D_ 128
#define H_ 4
#define M_ 8192            // B*S
#define SCALE2_ 0.25503472510324417f   // (1/sqrt(32)) * log2(e)
#define APO_ 0.2f
#define TRP_ 0.15f
#define EPS_ 1e-5f

__device__ __forceinline__ float fexp2(float x){ return __builtin_amdgcn_exp2f(x); }

__device__ __forceinline__ u16 f2bf(float f){
  unsigned u = __float_as_uint(f);
  unsigned r = ((u >> 16) & 1u) + 0x7fffu;     // round-to-nearest-even
  return (u16)((u + r) >> 16);
}
__device__ __forceinline__ float bf2f(u16 u){ return __uint_as_float(((unsigned)u) << 16); }
__device__ __forceinline__ float sigm(float x){ return 1.0f/(1.0f + __expf(-x)); }

// packed f32x2 -> bf16x2 (RNE), single VALU op. No builtin on gfx950; inline asm.
__device__ __forceinline__ unsigned cvtpk_bf16(float lo, float hi){
  unsigned r;
  asm("v_cvt_pk_bf16_f32 %0, %1, %2" : "=v"(r) : "v"(lo), "v"(hi));
  return r;
}

// Raw workgroup barrier: LDS-ordering only (lgkmcnt), no vmcnt drain — global
// prefetch loads stay in flight across it.
#define LDS_BARRIER() __asm__ volatile("s_waitcnt lgkmcnt(0)\n\ts_barrier" ::: "memory")

// ---------------------------------------------------------------- prep: weights cvt + ln1
struct WSrc { const float* s[13]; };
// order: Wq,Wk,Wv | Wo | Wg | Wt | Ws | Wr | Wop | W1 | W2 | Wsg | Wn
__global__ __launch_bounds__(256) void prep_k(WSrc w, u16* __restrict__ dst,
    const float* __restrict__ x_in, const float* __restrict__ g,
    const float* __restrict__ b, u16* __restrict__ cg0, float* __restrict__ colsum){
  if (blockIdx.x < 1168){
    // block 0 also zeroes the colsum accumulator (512 f32) for this launch
    if (blockIdx.x == 0 && threadIdx.x < 512) colsum[threadIdx.x] = 0.f;
    int idx = blockIdx.x*256 + threadIdx.x;
    if (idx >= 299008) return;
    const int sz[13] = {16384,16384,16384,16384,32768,8192,8192,12288,8192,65536,65536,16384,16384};
    int off = idx;
    #pragma unroll
    for (int seg = 0; seg < 13; ++seg){
      if (off < sz[seg]) { dst[idx] = f2bf(w.s[seg][off]); return; }
      off -= sz[seg];
    }
  } else {
    int wv = threadIdx.x >> 6, lane = threadIdx.x & 63;
    int row = (blockIdx.x - 1168)*4 + wv;
    size_t rb = (size_t)row * D_;
    float v0 = x_in[rb + lane], v1 = x_in[rb + lane + 64];
    float s = v0 + v1;
    #pragma unroll
    for (int m = 1; m < 64; m <<= 1) s += __shfl_xor(s, m, 64);
    float mean = s * (1.0f/128.0f);
    float d0 = v0 - mean, d1 = v1 - mean;
    float vv = d0*d0 + d1*d1;
    #pragma unroll
    for (int m = 1; m < 64; m <<= 1) vv += __shfl_xor(vv, m, 64);
    float rstd = rsqrtf(vv * (1.0f/128.0f) + EPS_);
    cg0[rb + lane]      = f2bf(d0*rstd*g[lane]    + b[lane]);
    cg0[rb + lane + 64] = f2bf(d1*rstd*g[lane+64] + b[lane+64]);
  }
}

// ---------------------------------------------------------------- QKV GEMM (first iter only)
__global__ __launch_bounds__(256) void gemm_qkv(const u16* __restrict__ A,
    const u16* __restrict__ W, u16* __restrict__ qh, u16* __restrict__ kh, u16* __restrict__ vt){
  __shared__ u16 Asm[64*136];
  __shared__ u16 Bsm[64*136];
  const int m0 = blockIdx.x*64, n0 = blockIdx.y*64;
  int tid = threadIdx.x;
  int wv = tid >> 6, lane = tid & 63, quad = lane >> 4, l15 = lane & 15;
  int wm = wv >> 1, wn = wv & 1;
  {
    int sr = tid >> 2, cb = (tid & 3)*32;
    const u16* ag = A + (size_t)(m0 + sr)*128 + cb;
    const u16* bg = W + (size_t)(n0 + sr)*128 + cb;
    short8 a0 = *(const short8*)(ag + 0);
    short8 a1 = *(const short8*)(ag + 8);
    short8 a2 = *(const short8*)(ag + 16);
    short8 a3 = *(const short8*)(ag + 24);
    short8 b0 = *(const short8*)(bg + 0);
    short8 b1 = *(const short8*)(bg + 8);
    short8 b2 = *(const short8*)(bg + 16);
    short8 b3 = *(const short8*)(bg + 24);
    *(short8*)(Asm + sr*136 + cb + 0)  = a0;
    *(short8*)(Asm + sr*136 + cb + 8)  = a1;
    *(short8*)(Asm + sr*136 + cb + 16) = a2;
    *(short8*)(Asm + sr*136 + cb + 24) = a3;
    *(short8*)(Bsm + sr*136 + cb + 0)  = b0;
    *(short8*)(Bsm + sr*136 + cb + 8)  = b1;
    *(short8*)(Bsm + sr*136 + cb + 16) = b2;
    *(short8*)(Bsm + sr*136 + cb + 24) = b3;
  }
  LDS_BARRIER();
  f32x4 acc[2][2];
  #pragma unroll
  for (int i = 0; i < 2; ++i)
    #pragma unroll
    for (int j = 0; j < 2; ++j) acc[i][j] = (f32x4){0.f,0.f,0.f,0.f};
  #pragma unroll
  for (int k0 = 0; k0 < 128; k0 += 32){
    short8 af0 = *(const short8*)(Asm + (wm*32      + l15)*136 + k0 + quad*8);
    short8 af1 = *(const short8*)(Asm + (wm*32 + 16 + l15)*136 + k0 + quad*8);
    short8 bf0 = *(const short8*)(Bsm + (wn*32      + l15)*136 + k0 + quad*8);
    short8 bf1 = *(const short8*)(Bsm + (wn*32 + 16 + l15)*136 + k0 + quad*8);
    acc[0][0] = __builtin_amdgcn_mfma_f32_16x16x32_bf16(af0, bf0, acc[0][0], 0,0,0);
    acc[0][1] = __builtin_amdgcn_mfma_f32_16x16x32_bf16(af0, bf1, acc[0][1], 0,0,0);
    acc[1][0] = __builtin_amdgcn_mfma_f32_16x16x32_bf16(af1, bf0, acc[1][0], 0,0,0);
    acc[1][1] = __builtin_amdgcn_mfma_f32_16x16x32_bf16(af1, bf1, acc[1][1], 0,0,0);
  }
  #pragma unroll
  for (int ms = 0; ms < 2; ++ms)
    #pragma unroll
    for (int ns = 0; ns < 2; ++ns){
      int mb = m0 + wm*32 + ms*16 + quad*4;
      int nn = n0 + wn*32 + ns*16 + l15;
      int which = nn >> 7, col = nn & 127, h = col >> 5, hd = col & 31;
      f32x4 c = acc[ms][ns];
      #pragma unroll
      for (int r = 0; r < 4; ++r){
        int m = mb + r, b = m >> 11, s = m & 2047;
        if (which == 0)      qh[((size_t)(b*H_+h)*S_ + s)*32 + hd] = f2bf(c[r]);
        else if (which == 1) kh[((size_t)(b*H_+h)*S_ + s)*32 + hd] = f2bf(c[r]);
        else                 vt[((size_t)(b*H_+h)*32 + hd)*S_ + s] = f2bf(c[r]);
      }
    }
}

// ---------------------------------------------------------------- fused attention
// K read DIRECT from global (wave-contiguous 1KB, L1-broadcast across the 4
// waves); V staged double-buffered in LDS (transpose gather), one lgkm-only
// barrier per chunk.  XCD-bijective block swizzle.  WRITE_AW: barrier-free
// LDS-free prepass computes lsum; normalization folded into the exponent.
template<bool WRITE_AW>
__global__ __launch_bounds__(256) void attn_k(const u16* __restrict__ qh, const u16* __restrict__ kh,
    const u16* __restrict__ vT, u16* __restrict__ ao_bf, float* __restrict__ aw){
  __shared__ u16 Vs[2][32*136];     // [hd][key] pitch 136
  __shared__ u16 Ps[4*16*136];      // per-wave P rows, pitch 136
  int L = blockIdx.y*32 + blockIdx.x;
  int xcd = L & 7, j = L >> 3;
  int bh = 2*xcd + (j >> 5);
  int q0 = (j & 31)*64;
  int b = bh >> 2, h = bh & 3;
  int tid = threadIdx.x, wv = tid >> 6, lane = tid & 63, quad = lane >> 4, l15 = lane & 15;
  int qrow = q0 + wv*16 + l15;
  const size_t bhS = (size_t)bh * S_;
  short8 qf = *(const short8*)(qh + (bhS + qrow)*32 + quad*8);
  const u16* kg = kh + bhS*32 + quad*8;                   // + key*32
  int vrow = tid >> 3, vseg = (tid & 7)*16;
  const u16* vg = vT + ((size_t)bh*32 + vrow)*S_ + vseg;  // + t*128
  f32x4 zero = {0.f,0.f,0.f,0.f};
  f32x4 ao0 = zero, ao1 = zero;
  float lsum = 0.f, rinv = 1.0f, nls = 0.f;
  u16* PsW = Ps + wv*16*136;

  if constexpr (WRITE_AW){
    // ---- prepass: lsum only — pure global-read stream, no LDS, no barriers
    #pragma unroll 4
    for (int kt = 0; kt < 128; ++kt){
      short8 kf = *(const short8*)(kg + (size_t)(kt*16 + l15)*32);
      f32x4 s = __builtin_amdgcn_mfma_f32_16x16x32_bf16(kf, qf, zero, 0,0,0);
      #pragma unroll
      for (int r = 0; r < 4; ++r) lsum += fexp2(s[r]*SCALE2_);
    }
    lsum += __shfl_xor(lsum, 16, 64);
    lsum += __shfl_xor(lsum, 32, 64);
    nls = -__log2f(lsum);
  }

  // ---- main pass: V staged (double-buffered), K direct
  {
    short8 b0 = *(const short8*)(vg + 0);
    short8 b1 = *(const short8*)(vg + 8);
    *(short8*)(Vs[0] + vrow*136 + vseg    ) = b0;
    *(short8*)(Vs[0] + vrow*136 + vseg + 8) = b1;
  }
  #pragma unroll 2
  for (int t = 0; t < 16; ++t){
    LDS_BARRIER();
    short8 vn0, vn1;
    if (t < 15){
      vn0 = *(const short8*)(vg + (size_t)(t+1)*128 + 0);
      vn1 = *(const short8*)(vg + (size_t)(t+1)*128 + 8);
    }
    const u16* Vb = Vs[t & 1];
    int k0 = t*128;
    #pragma unroll
    for (int jt = 0; jt < 8; ++jt){
      short8 kf = *(const short8*)(kg + (size_t)(k0 + jt*16 + l15)*32);
      f32x4 s = __builtin_amdgcn_mfma_f32_16x16x32_bf16(kf, qf, zero, 0,0,0);
      float pv[4];
      #pragma unroll
      for (int r = 0; r < 4; ++r){
        float e;
        if constexpr (WRITE_AW) e = fexp2(__builtin_fmaf(s[r], SCALE2_, nls));
        else { e = fexp2(s[r]*SCALE2_); lsum += e; }
        pv[r] = e;
      }
      if constexpr (WRITE_AW){
        f32x4 st = {pv[0], pv[1], pv[2], pv[3]};
        *(f32x4*)(aw + (bhS + qrow)*S_ + k0 + jt*16 + quad*4) = st;
      }
      uint32x2 pk;
      pk[0] = cvtpk_bf16(pv[0], pv[1]);
      pk[1] = cvtpk_bf16(pv[2], pv[3]);
      *(uint32x2*)(PsW + l15*136 + jt*16 + quad*4) = pk;
    }
    __asm__ volatile("s_waitcnt lgkmcnt(0)" ::: "memory");
    #pragma unroll
    for (int jg = 0; jg < 4; ++jg){
      short8 pf  = *(const short8*)(PsW + l15*136 + jg*32 + quad*8);
      short8 vf0 = *(const short8*)(Vb + (l15     )*136 + jg*32 + quad*8);
      short8 vf1 = *(const short8*)(Vb + (16 + l15)*136 + jg*32 + quad*8);
      ao0 = __builtin_amdgcn_mfma_f32_16x16x32_bf16(vf0, pf, ao0, 0,0,0);
      ao1 = __builtin_amdgcn_mfma_f32_16x16x32_bf16(vf1, pf, ao1, 0,0,0);
    }
    if (t < 15){
      u16* Vn = Vs[(t+1) & 1];
      *(short8*)(Vn + vrow*136 + vseg    ) = vn0;
      *(short8*)(Vn + vrow*136 + vseg + 8) = vn1;
    }
  }

  if constexpr (!WRITE_AW){
    lsum += __shfl_xor(lsum, 16, 64);
    lsum += __shfl_xor(lsum, 32, 64);
    rinv = 1.0f / lsum;
  }

  size_t rowbase = ((size_t)(b*S_ + qrow))*D_ + h*32;
  #pragma unroll
  for (int dt = 0; dt < 2; ++dt){
    f32x4 a = dt ? ao1 : ao0;
    uint32x2 pk;
    pk[0] = cvtpk_bf16(a[0]*rinv, a[1]*rinv);
    pk[1] = cvtpk_bf16(a[2]*rinv, a[3]*rinv);
    *(uint32x2*)(ao_bf + rowbase + dt*16 + quad*4) = pk;
  }
}

// ---------------------------------------------------------------- fused WO + gate (+ QKV | + ln2+colsum)
// DO_QKV=true : wowg + next-iter QKV GEMM from LDS (R7-proven).
// DO_QKV=false: final iter — fused ln2 (xbuf = x_in + cout, lnb = LN(xbuf))
//               + per-block column-sum of lnb accumulated into colsum[4][128]
//               via LDS reduce (reusing dead outS) + 128 atomicAdds.
template<bool DO_QKV>
__global__ __launch_bounds__(256) void wqkv_k(const u16* __restrict__ cin,
    const u16* __restrict__ ao_bf, const u16* __restrict__ wo, const u16* __restrict__ wg,
    const u16* __restrict__ w3, const float* __restrict__ bo, const float* __restrict__ bg,
    u16* __restrict__ cout, u16* __restrict__ qh, u16* __restrict__ kh, u16* __restrict__ vt,
    const float* __restrict__ x_in, const float* __restrict__ g_trp,
    const float* __restrict__ b_trp, float* __restrict__ xbuf, u16* __restrict__ lnb,
    float* __restrict__ colsum){
  __shared__ u16 aoS[16*136];
  __shared__ u16 cuS[16*136];
  __shared__ u16 outS[16*136];
  __shared__ u16 coS[16*136];
  const int m0 = blockIdx.x*16;
  int tid = threadIdx.x, wv = tid >> 6, lane = tid & 63, quad = lane >> 4, l15 = lane & 15;
  {
    int row = tid >> 4, seg = (tid & 15)*8;
    *(short8*)(aoS + row*136 + seg) = *(const short8*)(ao_bf + (size_t)(m0+row)*128 + seg);
    *(short8*)(cuS + row*136 + seg) = *(const short8*)(cin   + (size_t)(m0+row)*128 + seg);
  }
  __syncthreads();
  f32x4 oacc[2] = {(f32x4){0,0,0,0},(f32x4){0,0,0,0}};
  #pragma unroll
  for (int kc = 0; kc < 4; ++kc){
    short8 af = *(const short8*)(aoS + l15*136 + kc*32 + quad*8);
    #pragma unroll
    for (int nt = 0; nt < 2; ++nt){
      int n = wv*32 + nt*16 + l15;
      short8 bfv = *(const short8*)(wo + (size_t)n*128 + kc*32 + quad*8);
      oacc[nt] = __builtin_amdgcn_mfma_f32_16x16x32_bf16(af, bfv, oacc[nt], 0,0,0);
    }
  }
  #pragma unroll
  for (int nt = 0; nt < 2; ++nt){
    int n = wv*32 + nt*16 + l15;
    float bias = bo[n];
    #pragma unroll
    for (int r = 0; r < 4; ++r){
      int m = quad*4 + r;
      outS[m*136 + n] = f2bf(oacc[nt][r] + bias);
    }
  }
  __syncthreads();
  f32x4 gacc[2] = {(f32x4){0,0,0,0},(f32x4){0,0,0,0}};
  #pragma unroll
  for (int kc = 0; kc < 8; ++kc){
    short8 af = (kc < 4) ? *(const short8*)(cuS  + l15*136 + kc*32 + quad*8)
                         : *(const short8*)(outS + l15*136 + (kc-4)*32 + quad*8);
    #pragma unroll
    for (int nt = 0; nt < 2; ++nt){
      int n = wv*32 + nt*16 + l15;
      short8 bfv = *(const short8*)(wg + (size_t)n*256 + kc*32 + quad*8);
      gacc[nt] = __builtin_amdgcn_mfma_f32_16x16x32_bf16(af, bfv, gacc[nt], 0,0,0);
    }
  }
  #pragma unroll
  for (int nt = 0; nt < 2; ++nt){
    int n = wv*32 + nt*16 + l15;
    float biasg = bg[n], biaso = bo[n];
    #pragma unroll
    for (int r = 0; r < 4; ++r){
      int m = quad*4 + r;
      float g = sigm(gacc[nt][r] + biasg);
      float c = bf2f(cuS[m*136 + n]);
      float o = oacc[nt][r] + biaso;
      u16 val = f2bf(c + g*(o - c));
      coS[m*136 + n] = val;
      if constexpr (DO_QKV) cout[(size_t)(m0+m)*128 + n] = val;
    }
  }
  __syncthreads();
  if constexpr (DO_QKV){
    f32x4 qacc[6];
    #pragma unroll
    for (int i = 0; i < 6; ++i) qacc[i] = (f32x4){0,0,0,0};
    #pragma unroll
    for (int kc = 0; kc < 4; ++kc){
      short8 af = *(const short8*)(coS + l15*136 + kc*32 + quad*8);
      #pragma unroll
      for (int nt = 0; nt < 6; ++nt){
        int n = wv*96 + nt*16 + l15;
        short8 bfv = *(const short8*)(w3 + (size_t)n*128 + kc*32 + quad*8);
        qacc[nt] = __builtin_amdgcn_mfma_f32_16x16x32_bf16(af, bfv, qacc[nt], 0,0,0);
      }
    }
    #pragma unroll
    for (int nt = 0; nt < 6; ++nt){
      int nn = wv*96 + nt*16 + l15;
      int which = nn >> 7, col = nn & 127, h = col >> 5, hd = col & 31;
      #pragma unroll
      for (int r = 0; r < 4; ++r){
        int m = m0 + quad*4 + r, b = m >> 11, s = m & 2047;
        if (which == 0)      qh[((size_t)(b*H_+h)*S_ + s)*32 + hd] = f2bf(qacc[nt][r]);
        else if (which == 1) kh[((size_t)(b*H_+h)*S_ + s)*32 + hd] = f2bf(qacc[nt][r]);
        else                 vt[((size_t)(b*H_+h)*32 + hd)*S_ + s] = f2bf(qacc[nt][r]);
      }
    }
  } else {
    // fused ln2: x = x_in + cout ; xbuf = x ; lnb = LN(x)*g_trp + b_trp
    // + column sums of lnb into colsum[bidx][128]
    const int bidx = m0 >> 11;
    float cs0 = 0.f, cs1 = 0.f;
    for (int rr = wv*4; rr < wv*4 + 4; ++rr){
      size_t rb = (size_t)(m0+rr)*128;
      float v0 = x_in[rb + lane]      + bf2f(coS[rr*136 + lane]);
      float v1 = x_in[rb + lane + 64] + bf2f(coS[rr*136 + lane + 64]);
      xbuf[rb + lane] = v0; xbuf[rb + lane + 64] = v1;
      float s = v0 + v1;
      #pragma unroll
      for (int m = 1; m < 64; m <<= 1) s += __shfl_xor(s, m, 64);
      float mean = s * (1.0f/128.0f);
      float d0 = v0 - mean, d1 = v1 - mean;
      float vv = d0*d0 + d1*d1;
      #pragma unroll
      for (int m = 1; m < 64; m <<= 1) vv += __shfl_xor(vv, m, 64);
      float rstd = rsqrtf(vv * (1.0f/128.0f) + EPS_);
      u16 l0v = f2bf(d0*rstd*g_trp[lane]    + b_trp[lane]);
      u16 l1v = f2bf(d1*rstd*g_trp[lane+64] + b_trp[lane+64]);
      lnb[rb + lane]      = l0v;
      lnb[rb + lane + 64] = l1v;
      cs0 += bf2f(l0v);
      cs1 += bf2f(l1v);
    }
    float* red = (float*)outS;          // reuse dead outS: [4][128] f32 = 2 KB
    red[wv*128 + lane]      = cs0;
    red[wv*128 + lane + 64] = cs1;
    __syncthreads();
    if (tid < 128){
      float s = red[tid] + red[128 + tid] + red[256 + tid] + red[384 + tid];
      atomicAdd(&colsum[bidx*128 + tid], s);
    }
  }
}

// ---------------------------------------------------------------- uber: TRP+FFN+Apophasis
// cv/cn computed inline from colsum (wave 0, before first barrier).
__global__ __launch_bounds__(256) void uber_k(const u16* __restrict__ lnb,
    const float* __restrict__ space, const float* __restrict__ xbuf,
    const float* __restrict__ colsum, const float* __restrict__ Wc, const float* __restrict__ bc,
    const u16* __restrict__ wt, const float* __restrict__ bt,
    const u16* __restrict__ wsx, const float* __restrict__ bs,
    const u16* __restrict__ wr, const float* __restrict__ br, const float* __restrict__ fv,
    const u16* __restrict__ wop, const float* __restrict__ bop,
    const float* __restrict__ g_ffn, const float* __restrict__ b_ffn,
    const u16* __restrict__ w1, const float* __restrict__ b1,
    const u16* __restrict__ w2, const float* __restrict__ b2,
    const u16* __restrict__ wsg, const float* __restrict__ bsg,
    const float* __restrict__ g_apo, const float* __restrict__ b_apo,
    const u16* __restrict__ wn, const float* __restrict__ bn,
    float* __restrict__ out_x){
  __shared__ u16 xnS[16*136];     // lnb stage, later xn3, later xn4
  __shared__ u16 spS[16*136];     // space bf16
  __shared__ u16 CcS[16*200];     // [tv | cv | sv] bf16
  __shared__ float svF[16*64];
  __shared__ u16 RsS[16*72];
  __shared__ float xrF[16*128];   // xbuf rows f32, updated in place
  __shared__ u16 midS[16*536];
  __shared__ float alignS[16];
  __shared__ float cvS[64];
  __shared__ float cnS;
  const int m0 = blockIdx.x*16;
  const int bidx = m0 >> 11;
  int tid = threadIdx.x, wv = tid >> 6, lane = tid & 63, quad = lane >> 4, l15 = lane & 15;

  // ---- stage (+ wave 0 computes cv/cn from colsum)
  {
    int row = tid >> 4, seg = (tid & 15)*8;
    *(short8*)(xnS + row*136 + seg) = *(const short8*)(lnb + (size_t)(m0+row)*128 + seg);
    const float* sp = space + (size_t)(m0+row)*128 + seg;
    short8 pk;
    #pragma unroll
    for (int i = 0; i < 8; ++i) pk[i] = (short)f2bf(sp[i]);
    *(short8*)(spS + row*136 + seg) = pk;
    f32x4 xa = *(const f32x4*)(xbuf + (size_t)(m0+row)*128 + seg);
    f32x4 xb = *(const f32x4*)(xbuf + (size_t)(m0+row)*128 + seg + 4);
    *(f32x4*)(xrF + row*128 + seg) = xa;
    *(f32x4*)(xrF + row*128 + seg + 4) = xb;
  }
  if (tid < 64){
    const float* wrow = Wc + tid*128;
    const float* cb = colsum + bidx*128;
    float sacc = bc[tid];
    #pragma unroll 4
    for (int dd = 0; dd < 128; ++dd) sacc += (cb[dd]*(1.0f/2048.0f))*wrow[dd];
    cvS[tid] = sacc;
    float sq = sacc*sacc;
    #pragma unroll
    for (int m = 1; m < 64; m <<= 1) sq += __shfl_xor(sq, m, 64);
    if (tid == 0) cnS = fmaxf(sqrtf(sq), 1e-8f);
  }
  __syncthreads();

  // ---- S1: tv = xn2 @ Wt.T + bt
  f32x4 tvacc = {0,0,0,0};
  {
    int n = wv*16 + l15;
    #pragma unroll
    for (int kc = 0; kc < 4; ++kc){
      short8 af  = *(const short8*)(xnS + l15*136 + kc*32 + quad*8);
      short8 bfv = *(const short8*)(wt + (size_t)n*128 + kc*32 + quad*8);
      tvacc = __builtin_amdgcn_mfma_f32_16x16x32_bf16(af, bfv, tvacc, 0,0,0);
    }
    float bias = bt[n];
    #pragma unroll
    for (int r = 0; r < 4; ++r){
      tvacc[r] += bias;
      CcS[(quad*4 + r)*200 + n] = f2bf(tvacc[r]);
    }
  }
  // ---- S2: sv = space @ Ws.T + bs ; cv fill
  {
    int n = wv*16 + l15;
    f32x4 sva = {0,0,0,0};
    #pragma unroll
    for (int kc = 0; kc < 4; ++kc){
      short8 af  = *(const short8*)(spS + l15*136 + kc*32 + quad*8);
      short8 bfv = *(const short8*)(wsx + (size_t)n*128 + kc*32 + quad*8);
      sva = __builtin_amdgcn_mfma_f32_16x16x32_bf16(af, bfv, sva, 0,0,0);
    }
    float bias = bs[n];
    #pragma unroll
    for (int r = 0; r < 4; ++r){
      float v = sva[r] + bias;
      int m = quad*4 + r;
      CcS[m*200 + 128 + n] = f2bf(v);
      svF[m*64 + n] = v;
    }
    int row = tid >> 4, c4 = (tid & 15)*4;
    #pragma unroll
    for (int i = 0; i < 4; ++i)
      CcS[row*200 + 64 + c4 + i] = f2bf(cvS[c4 + i]);
  }
  __syncthreads();

  // ---- S3: align per row
  {
    float cnb = cnS;
    for (int rr = wv*4; rr < wv*4 + 4; ++rr){
      float s = svF[rr*64 + lane];
      float c = cvS[lane];
      float dot = c*s, ss = s*s;
      #pragma unroll
      for (int m = 1; m < 64; m <<= 1){ dot += __shfl_xor(dot, m, 64); ss += __shfl_xor(ss, m, 64); }
      if (lane == 0){
        float sn = fmaxf(sqrtf(ss), 1e-8f);
        alignS[rr] = dot / (cnb * sn);
      }
    }
  }
  __syncthreads();

  // ---- S4: rgate (K=192) -> resolved -> RsS
  {
    int n = wv*16 + l15;
    f32x4 ra = {0,0,0,0};
    #pragma unroll
    for (int kc = 0; kc < 6; ++kc){
      short8 af  = *(const short8*)(CcS + l15*200 + kc*32 + quad*8);
      short8 bfv = *(const short8*)(wr + (size_t)n*192 + kc*32 + quad*8);
      ra = __builtin_amdgcn_mfma_f32_16x16x32_bf16(af, bfv, ra, 0,0,0);
    }
    float bias = br[n], fvn = fv[n];
    #pragma unroll
    for (int r = 0; r < 4; ++r){
      int m = quad*4 + r;
      float rg = sigm(ra[r] + bias);
      float t = tvacc[r];
      float res = t + TRP_*(-alignS[m]*(fvn - t)*rg);
      RsS[m*72 + n] = f2bf(res);
    }
  }
  __syncthreads();

  // ---- S5: x += resolved @ Wop.T + bop
  {
    f32x4 wa[2] = {(f32x4){0,0,0,0},(f32x4){0,0,0,0}};
    #pragma unroll
    for (int kc = 0; kc < 2; ++kc){
      short8 af = *(const short8*)(RsS + l15*72 + kc*32 + quad*8);
      #pragma unroll
      for (int nt = 0; nt < 2; ++nt){
        int n = wv*32 + nt*16 + l15;
        short8 bfv = *(const short8*)(wop + (size_t)n*64 + kc*32 + quad*8);
        wa[nt] = __builtin_amdgcn_mfma_f32_16x16x32_bf16(af, bfv, wa[nt], 0,0,0);
      }
    }
    #pragma unroll
    for (int nt = 0; nt < 2; ++nt){
      int n = wv*32 + nt*16 + l15;
      float bias = bop[n];
      #pragma unroll
      for (int r = 0; r < 4; ++r){
        int m = quad*4 + r;
        xrF[m*128 + n] += wa[nt][r] + bias;
      }
    }
  }
  __syncthreads();

  // ---- S6: xn3 = LN(x) with g_ffn -> xnS
  for (int rr = wv*4; rr < wv*4 + 4; ++rr){
    float v0 = xrF[rr*128 + lane], v1 = xrF[rr*128 + lane + 64];
    float s = v0 + v1;
    #pragma unroll
    for (int m = 1; m < 64; m <<= 1) s += __shfl_xor(s, m, 64);
    float mean = s * (1.0f/128.0f);
    float d0 = v0 - mean, d1 = v1 - mean;
    float vvv = d0*d0 + d1*d1;
    #pragma unroll
    for (int m = 1; m < 64; m <<= 1) vvv += __shfl_xor(vvv, m, 64);
    float rstd = rsqrtf(vvv * (1.0f/128.0f) + EPS_);
    xnS[rr*136 + lane]      = f2bf(d0*rstd*g_ffn[lane]    + b_ffn[lane]);
    xnS[rr*136 + lane + 64] = f2bf(d1*rstd*g_ffn[lane+64] + b_ffn[lane+64]);
  }
  __syncthreads();

  // ---- S7: mid = gelu(xn3 @ W1.T + b1)
  {
    f32x4 acc[8];
    #pragma unroll
    for (int i = 0; i < 8; ++i) acc[i] = (f32x4){0,0,0,0};
    #pragma unroll
    for (int kc = 0; kc < 4; ++kc){
      short8 af = *(const short8*)(xnS + l15*136 + kc*32 + quad*8);
      #pragma unroll
      for (int nt = 0; nt < 8; ++nt){
        int n = wv*128 + nt*16 + l15;
        short8 bfv = *(const short8*)(w1 + (size_t)n*128 + kc*32 + quad*8);
        acc[nt] = __builtin_amdgcn_mfma_f32_16x16x32_bf16(af, bfv, acc[nt], 0,0,0);
      }
    }
    #pragma unroll
    for (int nt = 0; nt < 8; ++nt){
      int n = wv*128 + nt*16 + l15;
      float bias = b1[n];
      #pragma unroll
      for (int r = 0; r < 4; ++r){
        int m = quad*4 + r;
        float lin = acc[nt][r] + bias;
        float ge = 0.5f*lin*(1.0f + erff(lin*0.70710678118654752f));
        midS[m*536 + n] = f2bf(ge);
      }
    }
  }
  __syncthreads();

  // ---- S8+S9: ff = mid @ W2.T + b2 ; sg = sigm(xn3 @ Wsg.T + bsg); x += sg*ff
  {
    f32x4 ffa[2] = {(f32x4){0,0,0,0},(f32x4){0,0,0,0}};
    #pragma unroll
    for (int kc = 0; kc < 16; ++kc){
      short8 af = *(const short8*)(midS + l15*536 + kc*32 + quad*8);
      #pragma unroll
      for (int nt = 0; nt < 2; ++nt){
        int n = wv*32 + nt*16 + l15;
        short8 bfv = *(const short8*)(w2 + (size_t)n*512 + kc*32 + quad*8);
        ffa[nt] = __builtin_amdgcn_mfma_f32_16x16x32_bf16(af, bfv, ffa[nt], 0,0,0);
      }
    }
    f32x4 sga[2] = {(f32x4){0,0,0,0},(f32x4){0,0,0,0}};
    #pragma unroll
    for (int kc = 0; kc < 4; ++kc){
      short8 af = *(const short8*)(xnS + l15*136 + kc*32 + quad*8);
      #pragma unroll
      for (int nt = 0; nt < 2; ++nt){
        int n = wv*32 + nt*16 + l15;
        short8 bfv = *(const short8*)(wsg + (size_t)n*128 + kc*32 + quad*8);
        sga[nt] = __builtin_amdgcn_mfma_f32_16x16x32_bf16(af, bfv, sga[nt], 0,0,0);
      }
    }
    #pragma unroll
    for (int nt = 0; nt < 2; ++nt){
      int n = wv*32 + nt*16 + l15;
      float b2n = b2[n], bsgn = bsg[n];
      #pragma unroll
      for (int r = 0; r < 4; ++r){
        int m = quad*4 + r;
        float ff = ffa[nt][r] + b2n;
        float sg = sigm(sga[nt][r] + bsgn);
        xrF[m*128 + n] += sg*ff;
      }
    }
  }
  __syncthreads();

  // ---- S10: xn4 = LN(x) with g_apo -> xnS
  for (int rr = wv*4; rr < wv*4 + 4; ++rr){
    float v0 = xrF[rr*128 + lane], v1 = xrF[rr*128 + lane + 64];
    float s = v0 + v1;
    #pragma unroll
    for (int m = 1; m < 64; m <<= 1) s += __shfl_xor(s, m, 64);
    float mean = s * (1.0f/128.0f);
    float d0 = v0 - mean, d1 = v1 - mean;
    float vvv = d0*d0 + d1*d1;
    #pragma unroll
    for (int m = 1; m < 64; m <<= 1) vvv += __shfl_xor(vvv, m, 64);
    float rstd = rsqrtf(vvv * (1.0f/128.0f) + EPS_);
    xnS[rr*136 + lane]      = f2bf(d0*rstd*g_apo[lane]    + b_apo[lane]);
    xnS[rr*136 + lane + 64] = f2bf(d1*rstd*g_apo[lane+64] + b_apo[lane+64]);
  }
  __syncthreads();

  // ---- S11: out = x - APO*tanh(xn4 @ Wn.T + bn)
  {
    f32x4 na[2] = {(f32x4){0,0,0,0},(f32x4){0,0,0,0}};
    #pragma unroll
    for (int kc = 0; kc < 4; ++kc){
      short8 af = *(const short8*)(xnS + l15*136 + kc*32 + quad*8);
      #pragma unroll
      for (int nt = 0; nt < 2; ++nt){
        int n = wv*32 + nt*16 + l15;
        short8 bfv = *(const short8*)(wn + (size_t)n*128 + kc*32 + quad*8);
        na[nt] = __builtin_amdgcn_mfma_f32_16x16x32_bf16(af, bfv, na[nt], 0,0,0);
      }
    }
    #pragma unroll
    for (int nt = 0; nt < 2; ++nt){
      int n = wv*32 + nt*16 + l15;
      float bias = bn[n];
      #pragma unroll
      for (int r = 0; r < 4; ++r){
        int m = quad*4 + r;
        out_x[(size_t)(m0+m)*128 + n] = xrF[m*128 + n] - APO_*tanhf(na[nt][r] + bias);
      }
    }
  }
}

// ---------------------------------------------------------------- launch
extern "C" void kernel_launch(void* const* d_in, const int* in_sizes, int n_in,
                              void* d_out, int out_size, void* d_ws, size_t ws_size,
                              hipStream_t stream){
  (void)in_sizes; (void)n_in; (void)out_size; (void)ws_size;
  const float* x_in   = (const float*)d_in[0];
  const float* space  = (const float*)d_in[1];
  const float* g_attn = (const float*)d_in[2];
  const float* b_attn = (const float*)d_in[3];
  const float* Wq     = (const float*)d_in[4];
  const float* Wk     = (const float*)d_in[5];
  const float* Wv     = (const float*)d_in[6];
  const float* Wo     = (const float*)d_in[7];
  const float* bo     = (const float*)d_in[8];
  const float* Wg     = (const float*)d_in[9];
  const float* bg     = (const float*)d_in[10];
  const float* g_trp  = (const float*)d_in[13];
  const float* b_trp  = (const float*)d_in[14];
  const float* Wt     = (const float*)d_in[15];
  const float* bt     = (const float*)d_in[16];
  const float* Wc     = (const float*)d_in[17];
  const float* bc     = (const float*)d_in[18];
  const float* Ws_    = (const float*)d_in[19];
  const float* bs     = (const float*)d_in[20];
  const float* Wr     = (const float*)d_in[21];
  const float* br     = (const float*)d_in[22];
  const float* fv     = (const float*)d_in[23];
  const float* Wop    = (const float*)d_in[24];
  const float* bop    = (const float*)d_in[25];
  const float* g_ffn  = (const float*)d_in[26];
  const float* b_ffn  = (const float*)d_in[27];
  const float* W1_    = (const float*)d_in[28];
  const float* b1     = (const float*)d_in[29];
  const float* W2_    = (const float*)d_in[30];
  const float* b2     = (const float*)d_in[31];
  const float* Wsg_   = (const float*)d_in[32];
  const float* bsg    = (const float*)d_in[33];
  const float* g_apo  = (const float*)d_in[34];
  const float* b_apo  = (const float*)d_in[35];
  const float* Wn_    = (const float*)d_in[36];
  const float* bn     = (const float*)d_in[37];

  char* base = (char*)d_ws;
  size_t off = 0;
  auto alloc = [&](size_t bytes)->char* {
    char* r = base + off; off += (bytes + 255) & ~(size_t)255; return r; };
  u16*  wbf   = (u16*) alloc((size_t)299008*2);
  u16*  cg0   = (u16*) alloc((size_t)M_*D_*2);
  u16*  cg1   = (u16*) alloc((size_t)M_*D_*2);
  u16*  qh    = (u16*) alloc((size_t)16*S_*32*2);
  u16*  kh    = (u16*) alloc((size_t)16*S_*32*2);
  u16*  vt    = (u16*) alloc((size_t)16*32*S_*2);
  u16*  ao_bf = (u16*) alloc((size_t)M_*D_*2);
  u16*  lnb   = (u16*) alloc((size_t)M_*D_*2);
  float* xbuf = (float*)alloc((size_t)M_*D_*4);
  float* colsum = (float*)alloc(4*128*4);

  u16* wqkv = wbf;           // [384,128]
  u16* wo   = wbf + 49152;   // [128,128]
  u16* wg   = wbf + 65536;   // [128,256]
  u16* wt   = wbf + 98304;   // [64,128]
  u16* wsx  = wbf + 106496;  // [64,128]
  u16* wr   = wbf + 114688;  // [64,192]
  u16* wop  = wbf + 126976;  // [128,64]
  u16* w1   = wbf + 135168;  // [512,128]
  u16* w2   = wbf + 200704;  // [128,512]
  u16* wsgp = wbf + 266240;  // [128,128]
  u16* wn   = wbf + 282624;  // [128,128]

  float* out_x = (float*)d_out;
  float* aw    = out_x + (size_t)M_*D_;

  WSrc wsrc;
  wsrc.s[0]=Wq; wsrc.s[1]=Wk; wsrc.s[2]=Wv; wsrc.s[3]=Wo; wsrc.s[4]=Wg;
  wsrc.s[5]=Wt; wsrc.s[6]=Ws_; wsrc.s[7]=Wr; wsrc.s[8]=Wop; wsrc.s[9]=W1_;
  wsrc.s[10]=W2_; wsrc.s[11]=Wsg_; wsrc.s[12]=Wn_;

  prep_k<<<1168 + M_/4, 256, 0, stream>>>(wsrc, wbf, x_in, g_attn, b_attn, cg0, colsum);
  gemm_qkv<<<dim3(M_/64, 6), 256, 0, stream>>>(cg0, wqkv, qh, kh, vt);

  attn_k<false><<<dim3(S_/64, 16), 256, 0, stream>>>(qh, kh, vt, ao_bf, nullptr);
  wqkv_k<true ><<<M_/16, 256, 0, stream>>>(cg0, ao_bf, wo, wg, wqkv, bo, bg, cg1, qh, kh, vt,
                                           x_in, g_trp, b_trp, xbuf, lnb, colsum);
  attn_k<false><<<dim3(S_/64, 16), 256, 0, stream>>>(qh, kh, vt, ao_bf, nullptr);
  wqkv_k<true ><<<M_/16, 256, 0, stream>>>(cg1, ao_bf, wo, wg, wqkv, bo, bg, cg0, qh, kh, vt,
                                           x_in, g_trp, b_trp, xbuf, lnb, colsum);
  attn_k<true ><<<dim3(S_/64, 16), 256, 0, stream>>>(qh, kh, vt, ao_bf, aw);
  wqkv_k<false><<<M_/16, 256, 0, stream>>>(cg0, ao_bf, wo, wg, wqkv, bo, bg, cg1, qh, kh, vt,
                                           x_in, g_trp, b_trp, xbuf, lnb, colsum);

  uber_k<<<M_/16, 256, 0, stream>>>(lnb, space, xbuf, colsum, Wc, bc,
      wt, bt, wsx, bs, wr, br, fv, wop, bop,
      g_ffn, b_ffn, w1, b1, w2, b2, wsgp, bsg,
      g_apo, b_apo, wn, bn, out_x);
}

// Round 10
// 206.531 us; speedup vs baseline: 1.1329x; 1.1329x over previous
//
#include <hip/hip_runtime.h>
#include <cstdint>
#include <cstddef>

// ---------------------------------------------------------------------------
// DHSEncoderLayer on MI355X (gfx950).  Round 13 = exact revert to Round 11
// (207.6 us, best verified).  R12's K-destaging REVERTED: cooperative LDS
// staging of K amortizes global-load issue across the 4 waves (2 loads/thread
// staged vs 8 per-wave fragment loads destaged) — it was load-bearing.
// B=4,S=2048,D=128,H=4,HD=32,V=64, ITERS=3. Outputs: x [B,S,D] f32, aw [B,H,S,S] f32.
// 9 dispatches: prep, qkv, [attn, wqkv]x3(last wqkv does ln2+colsum), uber.
// ---------------------------------------------------------------------------

typedef unsigned short u16;
typedef __attribute__((ext_vector_type(8))) short short8;   // 8 x bf16
typedef __attribute__((ext_vector_type(4))) float f32x4;
typedef __attribute__((ext_vector_type(2))) unsigned uint32x2;

#define B_ 4
#define S_ 2048
#define D_ 128
#define H_ 4
#define M_ 8192            // B*S
#define SCALE2_ 0.25503472510324417f   // (1/sqrt(32)) * log2(e)
#define APO_ 0.2f
#define TRP_ 0.15f
#define EPS_ 1e-5f

__device__ __forceinline__ float fexp2(float x){ return __builtin_amdgcn_exp2f(x); }

__device__ __forceinline__ u16 f2bf(float f){
  unsigned u = __float_as_uint(f);
  unsigned r = ((u >> 16) & 1u) + 0x7fffu;     // round-to-nearest-even
  return (u16)((u + r) >> 16);
}
__device__ __forceinline__ float bf2f(u16 u){ return __uint_as_float(((unsigned)u) << 16); }
__device__ __forceinline__ float sigm(float x){ return 1.0f/(1.0f + __expf(-x)); }

// packed f32x2 -> bf16x2 (RNE), single VALU op. No builtin on gfx950; inline asm.
__device__ __forceinline__ unsigned cvtpk_bf16(float lo, float hi){
  unsigned r;
  asm("v_cvt_pk_bf16_f32 %0, %1, %2" : "=v"(r) : "v"(lo), "v"(hi));
  return r;
}

// Raw workgroup barrier: LDS-ordering only (lgkmcnt), no vmcnt drain — global
// prefetch loads stay in flight across it.
#define LDS_BARRIER() __asm__ volatile("s_waitcnt lgkmcnt(0)\n\ts_barrier" ::: "memory")

// ---------------------------------------------------------------- prep: weights cvt + ln1
struct WSrc { const float* s[13]; };
// order: Wq,Wk,Wv | Wo | Wg | Wt | Ws | Wr | Wop | W1 | W2 | Wsg | Wn
__global__ __launch_bounds__(256) void prep_k(WSrc w, u16* __restrict__ dst,
    const float* __restrict__ x_in, const float* __restrict__ g,
    const float* __restrict__ b, u16* __restrict__ cg0, float* __restrict__ colsum){
  if (blockIdx.x < 1168){
    // block 0 also zeroes the colsum accumulator (512 f32) for this launch
    if (blockIdx.x == 0 && threadIdx.x < 512) colsum[threadIdx.x] = 0.f;
    int idx = blockIdx.x*256 + threadIdx.x;
    if (idx >= 299008) return;
    const int sz[13] = {16384,16384,16384,16384,32768,8192,8192,12288,8192,65536,65536,16384,16384};
    int off = idx;
    #pragma unroll
    for (int seg = 0; seg < 13; ++seg){
      if (off < sz[seg]) { dst[idx] = f2bf(w.s[seg][off]); return; }
      off -= sz[seg];
    }
  } else {
    int wv = threadIdx.x >> 6, lane = threadIdx.x & 63;
    int row = (blockIdx.x - 1168)*4 + wv;
    size_t rb = (size_t)row * D_;
    float v0 = x_in[rb + lane], v1 = x_in[rb + lane + 64];
    float s = v0 + v1;
    #pragma unroll
    for (int m = 1; m < 64; m <<= 1) s += __shfl_xor(s, m, 64);
    float mean = s * (1.0f/128.0f);
    float d0 = v0 - mean, d1 = v1 - mean;
    float vv = d0*d0 + d1*d1;
    #pragma unroll
    for (int m = 1; m < 64; m <<= 1) vv += __shfl_xor(vv, m, 64);
    float rstd = rsqrtf(vv * (1.0f/128.0f) + EPS_);
    cg0[rb + lane]      = f2bf(d0*rstd*g[lane]    + b[lane]);
    cg0[rb + lane + 64] = f2bf(d1*rstd*g[lane+64] + b[lane+64]);
  }
}

// ---------------------------------------------------------------- QKV GEMM (first iter only)
__global__ __launch_bounds__(256) void gemm_qkv(const u16* __restrict__ A,
    const u16* __restrict__ W, u16* __restrict__ qh, u16* __restrict__ kh, u16* __restrict__ vt){
  __shared__ u16 Asm[64*136];
  __shared__ u16 Bsm[64*136];
  const int m0 = blockIdx.x*64, n0 = blockIdx.y*64;
  int tid = threadIdx.x;
  int wv = tid >> 6, lane = tid & 63, quad = lane >> 4, l15 = lane & 15;
  int wm = wv >> 1, wn = wv & 1;
  {
    int sr = tid >> 2, cb = (tid & 3)*32;
    const u16* ag = A + (size_t)(m0 + sr)*128 + cb;
    const u16* bg = W + (size_t)(n0 + sr)*128 + cb;
    short8 a0 = *(const short8*)(ag + 0);
    short8 a1 = *(const short8*)(ag + 8);
    short8 a2 = *(const short8*)(ag + 16);
    short8 a3 = *(const short8*)(ag + 24);
    short8 b0 = *(const short8*)(bg + 0);
    short8 b1 = *(const short8*)(bg + 8);
    short8 b2 = *(const short8*)(bg + 16);
    short8 b3 = *(const short8*)(bg + 24);
    *(short8*)(Asm + sr*136 + cb + 0)  = a0;
    *(short8*)(Asm + sr*136 + cb + 8)  = a1;
    *(short8*)(Asm + sr*136 + cb + 16) = a2;
    *(short8*)(Asm + sr*136 + cb + 24) = a3;
    *(short8*)(Bsm + sr*136 + cb + 0)  = b0;
    *(short8*)(Bsm + sr*136 + cb + 8)  = b1;
    *(short8*)(Bsm + sr*136 + cb + 16) = b2;
    *(short8*)(Bsm + sr*136 + cb + 24) = b3;
  }
  LDS_BARRIER();
  f32x4 acc[2][2];
  #pragma unroll
  for (int i = 0; i < 2; ++i)
    #pragma unroll
    for (int j = 0; j < 2; ++j) acc[i][j] = (f32x4){0.f,0.f,0.f,0.f};
  #pragma unroll
  for (int k0 = 0; k0 < 128; k0 += 32){
    short8 af0 = *(const short8*)(Asm + (wm*32      + l15)*136 + k0 + quad*8);
    short8 af1 = *(const short8*)(Asm + (wm*32 + 16 + l15)*136 + k0 + quad*8);
    short8 bf0 = *(const short8*)(Bsm + (wn*32      + l15)*136 + k0 + quad*8);
    short8 bf1 = *(const short8*)(Bsm + (wn*32 + 16 + l15)*136 + k0 + quad*8);
    acc[0][0] = __builtin_amdgcn_mfma_f32_16x16x32_bf16(af0, bf0, acc[0][0], 0,0,0);
    acc[0][1] = __builtin_amdgcn_mfma_f32_16x16x32_bf16(af0, bf1, acc[0][1], 0,0,0);
    acc[1][0] = __builtin_amdgcn_mfma_f32_16x16x32_bf16(af1, bf0, acc[1][0], 0,0,0);
    acc[1][1] = __builtin_amdgcn_mfma_f32_16x16x32_bf16(af1, bf1, acc[1][1], 0,0,0);
  }
  #pragma unroll
  for (int ms = 0; ms < 2; ++ms)
    #pragma unroll
    for (int ns = 0; ns < 2; ++ns){
      int mb = m0 + wm*32 + ms*16 + quad*4;
      int nn = n0 + wn*32 + ns*16 + l15;
      int which = nn >> 7, col = nn & 127, h = col >> 5, hd = col & 31;
      f32x4 c = acc[ms][ns];
      #pragma unroll
      for (int r = 0; r < 4; ++r){
        int m = mb + r, b = m >> 11, s = m & 2047;
        if (which == 0)      qh[((size_t)(b*H_+h)*S_ + s)*32 + hd] = f2bf(c[r]);
        else if (which == 1) kh[((size_t)(b*H_+h)*S_ + s)*32 + hd] = f2bf(c[r]);
        else                 vt[((size_t)(b*H_+h)*32 + hd)*S_ + s] = f2bf(c[r]);
      }
    }
}

// ---------------------------------------------------------------- fused attention
// R5 structure (staged, double-buffered, lgkm-only barriers) + XCD-bijective
// block swizzle. WRITE_AW: normalization folded into the exponent.
template<bool WRITE_AW>
__global__ __launch_bounds__(256) void attn_k(const u16* __restrict__ qh, const u16* __restrict__ kh,
    const u16* __restrict__ vT, u16* __restrict__ ao_bf, float* __restrict__ aw){
  __shared__ u16 Ks[2][128*40];     // [key][hd] pitch 40
  __shared__ u16 Vs[2][32*136];     // [hd][key] pitch 136
  __shared__ u16 Ps[4*16*136];      // per-wave P rows, pitch 136
  int L = blockIdx.y*32 + blockIdx.x;
  int xcd = L & 7, j = L >> 3;
  int bh = 2*xcd + (j >> 5);
  int q0 = (j & 31)*64;
  int b = bh >> 2, h = bh & 3;
  int tid = threadIdx.x, wv = tid >> 6, lane = tid & 63, quad = lane >> 4, l15 = lane & 15;
  int qrow = q0 + wv*16 + l15;
  const size_t bhS = (size_t)bh * S_;
  short8 qf = *(const short8*)(qh + (bhS + qrow)*32 + quad*8);
  int krow = tid >> 1, kseg = (tid & 1)*16;
  const u16* kg = kh + (bhS + krow)*32 + kseg;            // + t*4096
  int vrow = tid >> 3, vseg = (tid & 7)*16;
  const u16* vg = vT + ((size_t)bh*32 + vrow)*S_ + vseg;  // + t*128
  f32x4 zero = {0.f,0.f,0.f,0.f};
  f32x4 ao0 = zero, ao1 = zero;
  float lsum = 0.f, rinv = 1.0f, nls = 0.f;
  u16* PsW = Ps + wv*16*136;

  if constexpr (WRITE_AW){
    {
      short8 a0 = *(const short8*)(kg + 0);
      short8 a1 = *(const short8*)(kg + 8);
      *(short8*)(Ks[0] + krow*40 + kseg    ) = a0;
      *(short8*)(Ks[0] + krow*40 + kseg + 8) = a1;
    }
    #pragma unroll 2
    for (int t = 0; t < 16; ++t){
      LDS_BARRIER();
      short8 n0, n1;
      if (t < 15){
        n0 = *(const short8*)(kg + (size_t)(t+1)*4096 + 0);
        n1 = *(const short8*)(kg + (size_t)(t+1)*4096 + 8);
      }
      const u16* Kb = Ks[t & 1];
      #pragma unroll
      for (int jt = 0; jt < 8; ++jt){
        short8 kf = *(const short8*)(Kb + (jt*16 + l15)*40 + quad*8);
        f32x4 s = __builtin_amdgcn_mfma_f32_16x16x32_bf16(kf, qf, zero, 0,0,0);
        #pragma unroll
        for (int r = 0; r < 4; ++r) lsum += fexp2(s[r]*SCALE2_);
      }
      if (t < 15){
        u16* Kn = Ks[(t+1) & 1];
        *(short8*)(Kn + krow*40 + kseg    ) = n0;
        *(short8*)(Kn + krow*40 + kseg + 8) = n1;
      }
    }
    lsum += __shfl_xor(lsum, 16, 64);
    lsum += __shfl_xor(lsum, 32, 64);
    nls = -__log2f(lsum);
    LDS_BARRIER();
  }

  {
    short8 a0 = *(const short8*)(kg + 0);
    short8 a1 = *(const short8*)(kg + 8);
    short8 b0 = *(const short8*)(vg + 0);
    short8 b1 = *(const short8*)(vg + 8);
    *(short8*)(Ks[0] + krow*40 + kseg    ) = a0;
    *(short8*)(Ks[0] + krow*40 + kseg + 8) = a1;
    *(short8*)(Vs[0] + vrow*136 + vseg    ) = b0;
    *(short8*)(Vs[0] + vrow*136 + vseg + 8) = b1;
  }
  #pragma unroll 2
  for (int t = 0; t < 16; ++t){
    LDS_BARRIER();
    short8 kn0, kn1, vn0, vn1;
    if (t < 15){
      kn0 = *(const short8*)(kg + (size_t)(t+1)*4096 + 0);
      kn1 = *(const short8*)(kg + (size_t)(t+1)*4096 + 8);
      vn0 = *(const short8*)(vg + (size_t)(t+1)*128 + 0);
      vn1 = *(const short8*)(vg + (size_t)(t+1)*128 + 8);
    }
    const u16* Kb = Ks[t & 1];
    const u16* Vb = Vs[t & 1];
    int k0 = t*128;
    #pragma unroll
    for (int jt = 0; jt < 8; ++jt){
      short8 kf = *(const short8*)(Kb + (jt*16 + l15)*40 + quad*8);
      f32x4 s = __builtin_amdgcn_mfma_f32_16x16x32_bf16(kf, qf, zero, 0,0,0);
      float pv[4];
      #pragma unroll
      for (int r = 0; r < 4; ++r){
        float e;
        if constexpr (WRITE_AW) e = fexp2(__builtin_fmaf(s[r], SCALE2_, nls));
        else { e = fexp2(s[r]*SCALE2_); lsum += e; }
        pv[r] = e;
      }
      if constexpr (WRITE_AW){
        f32x4 st = {pv[0], pv[1], pv[2], pv[3]};
        *(f32x4*)(aw + (bhS + qrow)*S_ + k0 + jt*16 + quad*4) = st;
      }
      uint32x2 pk;
      pk[0] = cvtpk_bf16(pv[0], pv[1]);
      pk[1] = cvtpk_bf16(pv[2], pv[3]);
      *(uint32x2*)(PsW + l15*136 + jt*16 + quad*4) = pk;
    }
    __asm__ volatile("s_waitcnt lgkmcnt(0)" ::: "memory");
    #pragma unroll
    for (int jg = 0; jg < 4; ++jg){
      short8 pf  = *(const short8*)(PsW + l15*136 + jg*32 + quad*8);
      short8 vf0 = *(const short8*)(Vb + (l15     )*136 + jg*32 + quad*8);
      short8 vf1 = *(const short8*)(Vb + (16 + l15)*136 + jg*32 + quad*8);
      ao0 = __builtin_amdgcn_mfma_f32_16x16x32_bf16(vf0, pf, ao0, 0,0,0);
      ao1 = __builtin_amdgcn_mfma_f32_16x16x32_bf16(vf1, pf, ao1, 0,0,0);
    }
    if (t < 15){
      u16* Kn = Ks[(t+1) & 1];
      u16* Vn = Vs[(t+1) & 1];
      *(short8*)(Kn + krow*40 + kseg    ) = kn0;
      *(short8*)(Kn + krow*40 + kseg + 8) = kn1;
      *(short8*)(Vn + vrow*136 + vseg    ) = vn0;
      *(short8*)(Vn + vrow*136 + vseg + 8) = vn1;
    }
  }

  if constexpr (!WRITE_AW){
    lsum += __shfl_xor(lsum, 16, 64);
    lsum += __shfl_xor(lsum, 32, 64);
    rinv = 1.0f / lsum;
  }

  size_t rowbase = ((size_t)(b*S_ + qrow))*D_ + h*32;
  #pragma unroll
  for (int dt = 0; dt < 2; ++dt){
    f32x4 a = dt ? ao1 : ao0;
    uint32x2 pk;
    pk[0] = cvtpk_bf16(a[0]*rinv, a[1]*rinv);
    pk[1] = cvtpk_bf16(a[2]*rinv, a[3]*rinv);
    *(uint32x2*)(ao_bf + rowbase + dt*16 + quad*4) = pk;
  }
}

// ---------------------------------------------------------------- fused WO + gate (+ QKV | + ln2+colsum)
// DO_QKV=true : wowg + next-iter QKV GEMM from LDS (R7-proven).
// DO_QKV=false: final iter — fused ln2 (xbuf = x_in + cout, lnb = LN(xbuf))
//               + per-block column-sum of lnb accumulated into colsum[4][128]
//               via LDS reduce (reusing dead outS) + 128 atomicAdds.
template<bool DO_QKV>
__global__ __launch_bounds__(256) void wqkv_k(const u16* __restrict__ cin,
    const u16* __restrict__ ao_bf, const u16* __restrict__ wo, const u16* __restrict__ wg,
    const u16* __restrict__ w3, const float* __restrict__ bo, const float* __restrict__ bg,
    u16* __restrict__ cout, u16* __restrict__ qh, u16* __restrict__ kh, u16* __restrict__ vt,
    const float* __restrict__ x_in, const float* __restrict__ g_trp,
    const float* __restrict__ b_trp, float* __restrict__ xbuf, u16* __restrict__ lnb,
    float* __restrict__ colsum){
  __shared__ u16 aoS[16*136];
  __shared__ u16 cuS[16*136];
  __shared__ u16 outS[16*136];
  __shared__ u16 coS[16*136];
  const int m0 = blockIdx.x*16;
  int tid = threadIdx.x, wv = tid >> 6, lane = tid & 63, quad = lane >> 4, l15 = lane & 15;
  {
    int row = tid >> 4, seg = (tid & 15)*8;
    *(short8*)(aoS + row*136 + seg) = *(const short8*)(ao_bf + (size_t)(m0+row)*128 + seg);
    *(short8*)(cuS + row*136 + seg) = *(const short8*)(cin   + (size_t)(m0+row)*128 + seg);
  }
  __syncthreads();
  f32x4 oacc[2] = {(f32x4){0,0,0,0},(f32x4){0,0,0,0}};
  #pragma unroll
  for (int kc = 0; kc < 4; ++kc){
    short8 af = *(const short8*)(aoS + l15*136 + kc*32 + quad*8);
    #pragma unroll
    for (int nt = 0; nt < 2; ++nt){
      int n = wv*32 + nt*16 + l15;
      short8 bfv = *(const short8*)(wo + (size_t)n*128 + kc*32 + quad*8);
      oacc[nt] = __builtin_amdgcn_mfma_f32_16x16x32_bf16(af, bfv, oacc[nt], 0,0,0);
    }
  }
  #pragma unroll
  for (int nt = 0; nt < 2; ++nt){
    int n = wv*32 + nt*16 + l15;
    float bias = bo[n];
    #pragma unroll
    for (int r = 0; r < 4; ++r){
      int m = quad*4 + r;
      outS[m*136 + n] = f2bf(oacc[nt][r] + bias);
    }
  }
  __syncthreads();
  f32x4 gacc[2] = {(f32x4){0,0,0,0},(f32x4){0,0,0,0}};
  #pragma unroll
  for (int kc = 0; kc < 8; ++kc){
    short8 af = (kc < 4) ? *(const short8*)(cuS  + l15*136 + kc*32 + quad*8)
                         : *(const short8*)(outS + l15*136 + (kc-4)*32 + quad*8);
    #pragma unroll
    for (int nt = 0; nt < 2; ++nt){
      int n = wv*32 + nt*16 + l15;
      short8 bfv = *(const short8*)(wg + (size_t)n*256 + kc*32 + quad*8);
      gacc[nt] = __builtin_amdgcn_mfma_f32_16x16x32_bf16(af, bfv, gacc[nt], 0,0,0);
    }
  }
  #pragma unroll
  for (int nt = 0; nt < 2; ++nt){
    int n = wv*32 + nt*16 + l15;
    float biasg = bg[n], biaso = bo[n];
    #pragma unroll
    for (int r = 0; r < 4; ++r){
      int m = quad*4 + r;
      float g = sigm(gacc[nt][r] + biasg);
      float c = bf2f(cuS[m*136 + n]);
      float o = oacc[nt][r] + biaso;
      u16 val = f2bf(c + g*(o - c));
      coS[m*136 + n] = val;
      if constexpr (DO_QKV) cout[(size_t)(m0+m)*128 + n] = val;
    }
  }
  __syncthreads();
  if constexpr (DO_QKV){
    f32x4 qacc[6];
    #pragma unroll
    for (int i = 0; i < 6; ++i) qacc[i] = (f32x4){0,0,0,0};
    #pragma unroll
    for (int kc = 0; kc < 4; ++kc){
      short8 af = *(const short8*)(coS + l15*136 + kc*32 + quad*8);
      #pragma unroll
      for (int nt = 0; nt < 6; ++nt){
        int n = wv*96 + nt*16 + l15;
        short8 bfv = *(const short8*)(w3 + (size_t)n*128 + kc*32 + quad*8);
        qacc[nt] = __builtin_amdgcn_mfma_f32_16x16x32_bf16(af, bfv, qacc[nt], 0,0,0);
      }
    }
    #pragma unroll
    for (int nt = 0; nt < 6; ++nt){
      int nn = wv*96 + nt*16 + l15;
      int which = nn >> 7, col = nn & 127, h = col >> 5, hd = col & 31;
      #pragma unroll
      for (int r = 0; r < 4; ++r){
        int m = m0 + quad*4 + r, b = m >> 11, s = m & 2047;
        if (which == 0)      qh[((size_t)(b*H_+h)*S_ + s)*32 + hd] = f2bf(qacc[nt][r]);
        else if (which == 1) kh[((size_t)(b*H_+h)*S_ + s)*32 + hd] = f2bf(qacc[nt][r]);
        else                 vt[((size_t)(b*H_+h)*32 + hd)*S_ + s] = f2bf(qacc[nt][r]);
      }
    }
  } else {
    // fused ln2: x = x_in + cout ; xbuf = x ; lnb = LN(x)*g_trp + b_trp
    // + column sums of lnb into colsum[bidx][128]
    const int bidx = m0 >> 11;
    float cs0 = 0.f, cs1 = 0.f;
    for (int rr = wv*4; rr < wv*4 + 4; ++rr){
      size_t rb = (size_t)(m0+rr)*128;
      float v0 = x_in[rb + lane]      + bf2f(coS[rr*136 + lane]);
      float v1 = x_in[rb + lane + 64] + bf2f(coS[rr*136 + lane + 64]);
      xbuf[rb + lane] = v0; xbuf[rb + lane + 64] = v1;
      float s = v0 + v1;
      #pragma unroll
      for (int m = 1; m < 64; m <<= 1) s += __shfl_xor(s, m, 64);
      float mean = s * (1.0f/128.0f);
      float d0 = v0 - mean, d1 = v1 - mean;
      float vv = d0*d0 + d1*d1;
      #pragma unroll
      for (int m = 1; m < 64; m <<= 1) vv += __shfl_xor(vv, m, 64);
      float rstd = rsqrtf(vv * (1.0f/128.0f) + EPS_);
      u16 l0v = f2bf(d0*rstd*g_trp[lane]    + b_trp[lane]);
      u16 l1v = f2bf(d1*rstd*g_trp[lane+64] + b_trp[lane+64]);
      lnb[rb + lane]      = l0v;
      lnb[rb + lane + 64] = l1v;
      cs0 += bf2f(l0v);
      cs1 += bf2f(l1v);
    }
    float* red = (float*)outS;          // reuse dead outS: [4][128] f32 = 2 KB
    red[wv*128 + lane]      = cs0;
    red[wv*128 + lane + 64] = cs1;
    __syncthreads();
    if (tid < 128){
      float s = red[tid] + red[128 + tid] + red[256 + tid] + red[384 + tid];
      atomicAdd(&colsum[bidx*128 + tid], s);
    }
  }
}

// ---------------------------------------------------------------- uber: TRP+FFN+Apophasis
// cv/cn computed inline from colsum (wave 0, before first barrier).
__global__ __launch_bounds__(256) void uber_k(const u16* __restrict__ lnb,
    const float* __restrict__ space, const float* __restrict__ xbuf,
    const float* __restrict__ colsum, const float* __restrict__ Wc, const float* __restrict__ bc,
    const u16* __restrict__ wt, const float* __restrict__ bt,
    const u16* __restrict__ wsx, const float* __restrict__ bs,
    const u16* __restrict__ wr, const float* __restrict__ br, const float* __restrict__ fv,
    const u16* __restrict__ wop, const float* __restrict__ bop,
    const float* __restrict__ g_ffn, const float* __restrict__ b_ffn,
    const u16* __restrict__ w1, const float* __restrict__ b1,
    const u16* __restrict__ w2, const float* __restrict__ b2,
    const u16* __restrict__ wsg, const float* __restrict__ bsg,
    const float* __restrict__ g_apo, const float* __restrict__ b_apo,
    const u16* __restrict__ wn, const float* __restrict__ bn,
    float* __restrict__ out_x){
  __shared__ u16 xnS[16*136];     // lnb stage, later xn3, later xn4
  __shared__ u16 spS[16*136];     // space bf16
  __shared__ u16 CcS[16*200];     // [tv | cv | sv] bf16
  __shared__ float svF[16*64];
  __shared__ u16 RsS[16*72];
  __shared__ float xrF[16*128];   // xbuf rows f32, updated in place
  __shared__ u16 midS[16*536];
  __shared__ float alignS[16];
  __shared__ float cvS[64];
  __shared__ float cnS;
  const int m0 = blockIdx.x*16;
  const int bidx = m0 >> 11;
  int tid = threadIdx.x, wv = tid >> 6, lane = tid & 63, quad = lane >> 4, l15 = lane & 15;

  // ---- stage (+ wave 0 computes cv/cn from colsum)
  {
    int row = tid >> 4, seg = (tid & 15)*8;
    *(short8*)(xnS + row*136 + seg) = *(const short8*)(lnb + (size_t)(m0+row)*128 + seg);
    const float* sp = space + (size_t)(m0+row)*128 + seg;
    short8 pk;
    #pragma unroll
    for (int i = 0; i < 8; ++i) pk[i] = (short)f2bf(sp[i]);
    *(short8*)(spS + row*136 + seg) = pk;
    f32x4 xa = *(const f32x4*)(xbuf + (size_t)(m0+row)*128 + seg);
    f32x4 xb = *(const f32x4*)(xbuf + (size_t)(m0+row)*128 + seg + 4);
    *(f32x4*)(xrF + row*128 + seg) = xa;
    *(f32x4*)(xrF + row*128 + seg + 4) = xb;
  }
  if (tid < 64){
    const float* wrow = Wc + tid*128;
    const float* cb = colsum + bidx*128;
    float sacc = bc[tid];
    #pragma unroll 4
    for (int dd = 0; dd < 128; ++dd) sacc += (cb[dd]*(1.0f/2048.0f))*wrow[dd];
    cvS[tid] = sacc;
    float sq = sacc*sacc;
    #pragma unroll
    for (int m = 1; m < 64; m <<= 1) sq += __shfl_xor(sq, m, 64);
    if (tid == 0) cnS = fmaxf(sqrtf(sq), 1e-8f);
  }
  __syncthreads();

  // ---- S1: tv = xn2 @ Wt.T + bt
  f32x4 tvacc = {0,0,0,0};
  {
    int n = wv*16 + l15;
    #pragma unroll
    for (int kc = 0; kc < 4; ++kc){
      short8 af  = *(const short8*)(xnS + l15*136 + kc*32 + quad*8);
      short8 bfv = *(const short8*)(wt + (size_t)n*128 + kc*32 + quad*8);
      tvacc = __builtin_amdgcn_mfma_f32_16x16x32_bf16(af, bfv, tvacc, 0,0,0);
    }
    float bias = bt[n];
    #pragma unroll
    for (int r = 0; r < 4; ++r){
      tvacc[r] += bias;
      CcS[(quad*4 + r)*200 + n] = f2bf(tvacc[r]);
    }
  }
  // ---- S2: sv = space @ Ws.T + bs ; cv fill
  {
    int n = wv*16 + l15;
    f32x4 sva = {0,0,0,0};
    #pragma unroll
    for (int kc = 0; kc < 4; ++kc){
      short8 af  = *(const short8*)(spS + l15*136 + kc*32 + quad*8);
      short8 bfv = *(const short8*)(wsx + (size_t)n*128 + kc*32 + quad*8);
      sva = __builtin_amdgcn_mfma_f32_16x16x32_bf16(af, bfv, sva, 0,0,0);
    }
    float bias = bs[n];
    #pragma unroll
    for (int r = 0; r < 4; ++r){
      float v = sva[r] + bias;
      int m = quad*4 + r;
      CcS[m*200 + 128 + n] = f2bf(v);
      svF[m*64 + n] = v;
    }
    int row = tid >> 4, c4 = (tid & 15)*4;
    #pragma unroll
    for (int i = 0; i < 4; ++i)
      CcS[row*200 + 64 + c4 + i] = f2bf(cvS[c4 + i]);
  }
  __syncthreads();

  // ---- S3: align per row
  {
    float cnb = cnS;
    for (int rr = wv*4; rr < wv*4 + 4; ++rr){
      float s = svF[rr*64 + lane];
      float c = cvS[lane];
      float dot = c*s, ss = s*s;
      #pragma unroll
      for (int m = 1; m < 64; m <<= 1){ dot += __shfl_xor(dot, m, 64); ss += __shfl_xor(ss, m, 64); }
      if (lane == 0){
        float sn = fmaxf(sqrtf(ss), 1e-8f);
        alignS[rr] = dot / (cnb * sn);
      }
    }
  }
  __syncthreads();

  // ---- S4: rgate (K=192) -> resolved -> RsS
  {
    int n = wv*16 + l15;
    f32x4 ra = {0,0,0,0};
    #pragma unroll
    for (int kc = 0; kc < 6; ++kc){
      short8 af  = *(const short8*)(CcS + l15*200 + kc*32 + quad*8);
      short8 bfv = *(const short8*)(wr + (size_t)n*192 + kc*32 + quad*8);
      ra = __builtin_amdgcn_mfma_f32_16x16x32_bf16(af, bfv, ra, 0,0,0);
    }
    float bias = br[n], fvn = fv[n];
    #pragma unroll
    for (int r = 0; r < 4; ++r){
      int m = quad*4 + r;
      float rg = sigm(ra[r] + bias);
      float t = tvacc[r];
      float res = t + TRP_*(-alignS[m]*(fvn - t)*rg);
      RsS[m*72 + n] = f2bf(res);
    }
  }
  __syncthreads();

  // ---- S5: x += resolved @ Wop.T + bop
  {
    f32x4 wa[2] = {(f32x4){0,0,0,0},(f32x4){0,0,0,0}};
    #pragma unroll
    for (int kc = 0; kc < 2; ++kc){
      short8 af = *(const short8*)(RsS + l15*72 + kc*32 + quad*8);
      #pragma unroll
      for (int nt = 0; nt < 2; ++nt){
        int n = wv*32 + nt*16 + l15;
        short8 bfv = *(const short8*)(wop + (size_t)n*64 + kc*32 + quad*8);
        wa[nt] = __builtin_amdgcn_mfma_f32_16x16x32_bf16(af, bfv, wa[nt], 0,0,0);
      }
    }
    #pragma unroll
    for (int nt = 0; nt < 2; ++nt){
      int n = wv*32 + nt*16 + l15;
      float bias = bop[n];
      #pragma unroll
      for (int r = 0; r < 4; ++r){
        int m = quad*4 + r;
        xrF[m*128 + n] += wa[nt][r] + bias;
      }
    }
  }
  __syncthreads();

  // ---- S6: xn3 = LN(x) with g_ffn -> xnS
  for (int rr = wv*4; rr < wv*4 + 4; ++rr){
    float v0 = xrF[rr*128 + lane], v1 = xrF[rr*128 + lane + 64];
    float s = v0 + v1;
    #pragma unroll
    for (int m = 1; m < 64; m <<= 1) s += __shfl_xor(s, m, 64);
    float mean = s * (1.0f/128.0f);
    float d0 = v0 - mean, d1 = v1 - mean;
    float vvv = d0*d0 + d1*d1;
    #pragma unroll
    for (int m = 1; m < 64; m <<= 1) vvv += __shfl_xor(vvv, m, 64);
    float rstd = rsqrtf(vvv * (1.0f/128.0f) + EPS_);
    xnS[rr*136 + lane]      = f2bf(d0*rstd*g_ffn[lane]    + b_ffn[lane]);
    xnS[rr*136 + lane + 64] = f2bf(d1*rstd*g_ffn[lane+64] + b_ffn[lane+64]);
  }
  __syncthreads();

  // ---- S7: mid = gelu(xn3 @ W1.T + b1)
  {
    f32x4 acc[8];
    #pragma unroll
    for (int i = 0; i < 8; ++i) acc[i] = (f32x4){0,0,0,0};
    #pragma unroll
    for (int kc = 0; kc < 4; ++kc){
      short8 af = *(const short8*)(xnS + l15*136 + kc*32 + quad*8);
      #pragma unroll
      for (int nt = 0; nt < 8; ++nt){
        int n = wv*128 + nt*16 + l15;
        short8 bfv = *(const short8*)(w1 + (size_t)n*128 + kc*32 + quad*8);
        acc[nt] = __builtin_amdgcn_mfma_f32_16x16x32_bf16(af, bfv, acc[nt], 0,0,0);
      }
    }
    #pragma unroll
    for (int nt = 0; nt < 8; ++nt){
      int n = wv*128 + nt*16 + l15;
      float bias = b1[n];
      #pragma unroll
      for (int r = 0; r < 4; ++r){
        int m = quad*4 + r;
        float lin = acc[nt][r] + bias;
        float ge = 0.5f*lin*(1.0f + erff(lin*0.70710678118654752f));
        midS[m*536 + n] = f2bf(ge);
      }
    }
  }
  __syncthreads();

  // ---- S8+S9: ff = mid @ W2.T + b2 ; sg = sigm(xn3 @ Wsg.T + bsg); x += sg*ff
  {
    f32x4 ffa[2] = {(f32x4){0,0,0,0},(f32x4){0,0,0,0}};
    #pragma unroll
    for (int kc = 0; kc < 16; ++kc){
      short8 af = *(const short8*)(midS + l15*536 + kc*32 + quad*8);
      #pragma unroll
      for (int nt = 0; nt < 2; ++nt){
        int n = wv*32 + nt*16 + l15;
        short8 bfv = *(const short8*)(w2 + (size_t)n*512 + kc*32 + quad*8);
        ffa[nt] = __builtin_amdgcn_mfma_f32_16x16x32_bf16(af, bfv, ffa[nt], 0,0,0);
      }
    }
    f32x4 sga[2] = {(f32x4){0,0,0,0},(f32x4){0,0,0,0}};
    #pragma unroll
    for (int kc = 0; kc < 4; ++kc){
      short8 af = *(const short8*)(xnS + l15*136 + kc*32 + quad*8);
      #pragma unroll
      for (int nt = 0; nt < 2; ++nt){
        int n = wv*32 + nt*16 + l15;
        short8 bfv = *(const short8*)(wsg + (size_t)n*128 + kc*32 + quad*8);
        sga[nt] = __builtin_amdgcn_mfma_f32_16x16x32_bf16(af, bfv, sga[nt], 0,0,0);
      }
    }
    #pragma unroll
    for (int nt = 0; nt < 2; ++nt){
      int n = wv*32 + nt*16 + l15;
      float b2n = b2[n], bsgn = bsg[n];
      #pragma unroll
      for (int r = 0; r < 4; ++r){
        int m = quad*4 + r;
        float ff = ffa[nt][r] + b2n;
        float sg = sigm(sga[nt][r] + bsgn);
        xrF[m*128 + n] += sg*ff;
      }
    }
  }
  __syncthreads();

  // ---- S10: xn4 = LN(x) with g_apo -> xnS
  for (int rr = wv*4; rr < wv*4 + 4; ++rr){
    float v0 = xrF[rr*128 + lane], v1 = xrF[rr*128 + lane + 64];
    float s = v0 + v1;
    #pragma unroll
    for (int m = 1; m < 64; m <<= 1) s += __shfl_xor(s, m, 64);
    float mean = s * (1.0f/128.0f);
    float d0 = v0 - mean, d1 = v1 - mean;
    float vvv = d0*d0 + d1*d1;
    #pragma unroll
    for (int m = 1; m < 64; m <<= 1) vvv += __shfl_xor(vvv, m, 64);
    float rstd = rsqrtf(vvv * (1.0f/128.0f) + EPS_);
    xnS[rr*136 + lane]      = f2bf(d0*rstd*g_apo[lane]    + b_apo[lane]);
    xnS[rr*136 + lane + 64] = f2bf(d1*rstd*g_apo[lane+64] + b_apo[lane+64]);
  }
  __syncthreads();

  // ---- S11: out = x - APO*tanh(xn4 @ Wn.T + bn)
  {
    f32x4 na[2] = {(f32x4){0,0,0,0},(f32x4){0,0,0,0}};
    #pragma unroll
    for (int kc = 0; kc < 4; ++kc){
      short8 af = *(const short8*)(xnS + l15*136 + kc*32 + quad*8);
      #pragma unroll
      for (int nt = 0; nt < 2; ++nt){
        int n = wv*32 + nt*16 + l15;
        short8 bfv = *(const short8*)(wn + (size_t)n*128 + kc*32 + quad*8);
        na[nt] = __builtin_amdgcn_mfma_f32_16x16x32_bf16(af, bfv, na[nt], 0,0,0);
      }
    }
    #pragma unroll
    for (int nt = 0; nt < 2; ++nt){
      int n = wv*32 + nt*16 + l15;
      float bias = bn[n];
      #pragma unroll
      for (int r = 0; r < 4; ++r){
        int m = quad*4 + r;
        out_x[(size_t)(m0+m)*128 + n] = xrF[m*128 + n] - APO_*tanhf(na[nt][r] + bias);
      }
    }
  }
}

// ---------------------------------------------------------------- launch
extern "C" void kernel_launch(void* const* d_in, const int* in_sizes, int n_in,
                              void* d_out, int out_size, void* d_ws, size_t ws_size,
                              hipStream_t stream){
  (void)in_sizes; (void)n_in; (void)out_size; (void)ws_size;
  const float* x_in   = (const float*)d_in[0];
  const float* space  = (const float*)d_in[1];
  const float* g_attn = (const float*)d_in[2];
  const float* b_attn = (const float*)d_in[3];
  const float* Wq     = (const float*)d_in[4];
  const float* Wk     = (const float*)d_in[5];
  const float* Wv     = (const float*)d_in[6];
  const float* Wo     = (const float*)d_in[7];
  const float* bo     = (const float*)d_in[8];
  const float* Wg     = (const float*)d_in[9];
  const float* bg     = (const float*)d_in[10];
  const float* g_trp  = (const float*)d_in[13];
  const float* b_trp  = (const float*)d_in[14];
  const float* Wt     = (const float*)d_in[15];
  const float* bt     = (const float*)d_in[16];
  const float* Wc     = (const float*)d_in[17];
  const float* bc     = (const float*)d_in[18];
  const float* Ws_    = (const float*)d_in[19];
  const float* bs     = (const float*)d_in[20];
  const float* Wr     = (const float*)d_in[21];
  const float* br     = (const float*)d_in[22];
  const float* fv     = (const float*)d_in[23];
  const float* Wop    = (const float*)d_in[24];
  const float* bop    = (const float*)d_in[25];
  const float* g_ffn  = (const float*)d_in[26];
  const float* b_ffn  = (const float*)d_in[27];
  const float* W1_    = (const float*)d_in[28];
  const float* b1     = (const float*)d_in[29];
  const float* W2_    = (const float*)d_in[30];
  const float* b2     = (const float*)d_in[31];
  const float* Wsg_   = (const float*)d_in[32];
  const float* bsg    = (const float*)d_in[33];
  const float* g_apo  = (const float*)d_in[34];
  const float* b_apo  = (const float*)d_in[35];
  const float* Wn_    = (const float*)d_in[36];
  const float* bn     = (const float*)d_in[37];

  char* base = (char*)d_ws;
  size_t off = 0;
  auto alloc = [&](size_t bytes)->char* {
    char* r = base + off; off += (bytes + 255) & ~(size_t)255; return r; };
  u16*  wbf   = (u16*) alloc((size_t)299008*2);
  u16*  cg0   = (u16*) alloc((size_t)M_*D_*2);
  u16*  cg1   = (u16*) alloc((size_t)M_*D_*2);
  u16*  qh    = (u16*) alloc((size_t)16*S_*32*2);
  u16*  kh    = (u16*) alloc((size_t)16*S_*32*2);
  u16*  vt    = (u16*) alloc((size_t)16*32*S_*2);
  u16*  ao_bf = (u16*) alloc((size_t)M_*D_*2);
  u16*  lnb   = (u16*) alloc((size_t)M_*D_*2);
  float* xbuf = (float*)alloc((size_t)M_*D_*4);
  float* colsum = (float*)alloc(4*128*4);

  u16* wqkv = wbf;           // [384,128]
  u16* wo   = wbf + 49152;   // [128,128]
  u16* wg   = wbf + 65536;   // [128,256]
  u16* wt   = wbf + 98304;   // [64,128]
  u16* wsx  = wbf + 106496;  // [64,128]
  u16* wr   = wbf + 114688;  // [64,192]
  u16* wop  = wbf + 126976;  // [128,64]
  u16* w1   = wbf + 135168;  // [512,128]
  u16* w2   = wbf + 200704;  // [128,512]
  u16* wsgp = wbf + 266240;  // [128,128]
  u16* wn   = wbf + 282624;  // [128,128]

  float* out_x = (float*)d_out;
  float* aw    = out_x + (size_t)M_*D_;

  WSrc wsrc;
  wsrc.s[0]=Wq; wsrc.s[1]=Wk; wsrc.s[2]=Wv; wsrc.s[3]=Wo; wsrc.s[4]=Wg;
  wsrc.s[5]=Wt; wsrc.s[6]=Ws_; wsrc.s[7]=Wr; wsrc.s[8]=Wop; wsrc.s[9]=W1_;
  wsrc.s[10]=W2_; wsrc.s[11]=Wsg_; wsrc.s[12]=Wn_;

  prep_k<<<1168 + M_/4, 256, 0, stream>>>(wsrc, wbf, x_in, g_attn, b_attn, cg0, colsum);
  gemm_qkv<<<dim3(M_/64, 6), 256, 0, stream>>>(cg0, wqkv, qh, kh, vt);

  attn_k<false><<<dim3(S_/64, 16), 256, 0, stream>>>(qh, kh, vt, ao_bf, nullptr);
  wqkv_k<true ><<<M_/16, 256, 0, stream>>>(cg0, ao_bf, wo, wg, wqkv, bo, bg, cg1, qh, kh, vt,
                                           x_in, g_trp, b_trp, xbuf, lnb, colsum);
  attn_k<false><<<dim3(S_/64, 16), 256, 0, stream>>>(qh, kh, vt, ao_bf, nullptr);
  wqkv_k<true ><<<M_/16, 256, 0, stream>>>(cg1, ao_bf, wo, wg, wqkv, bo, bg, cg0, qh, kh, vt,
                                           x_in, g_trp, b_trp, xbuf, lnb, colsum);
  attn_k<true ><<<dim3(S_/64, 16), 256, 0, stream>>>(qh, kh, vt, ao_bf, aw);
  wqkv_k<false><<<M_/16, 256, 0, stream>>>(cg0, ao_bf, wo, wg, wqkv, bo, bg, cg1, qh, kh, vt,
                                           x_in, g_trp, b_trp, xbuf, lnb, colsum);

  uber_k<<<M_/16, 256, 0, stream>>>(lnb, space, xbuf, colsum, Wc, bc,
      wt, bt, wsx, bs, wr, br, fv, wop, bop,
      g_ffn, b_ffn, w1, b1, w2, b2, wsgp, bsg,
      g_apo, b_apo, wn, bn, out_x);
}